// Round 8
// baseline (136.166 us; speedup 1.0000x reference)
//
#include <hip/hip_runtime.h>

#define NUM_USER 100000
#define K_NEIGH 32
#define DIM 64
#define USERS_PER_BLOCK 16   // 256 threads / 16 lanes per user

typedef float floatx2 __attribute__((ext_vector_type(2)));
typedef float floatx4 __attribute__((ext_vector_type(4)));
typedef unsigned int uintx2 __attribute__((ext_vector_type(2)));
typedef unsigned int uintx4 __attribute__((ext_vector_type(4)));

__device__ __forceinline__ unsigned int pack_bf16(float a, float b) {
  unsigned int ua = __float_as_uint(a), ub = __float_as_uint(b);
  // round-to-nearest-even to bf16
  unsigned int ra = (ua + 0x7fffu + ((ua >> 16) & 1u)) >> 16;
  unsigned int rb = (ub + 0x7fffu + ((ub >> 16) & 1u)) >> 16;
  return ra | (rb << 16);
}

// ---------------------------------------------------------------------------
// Session model (rounds 0-7):
//  * Harness overhead ~76us CONSTANT; only total kernel time matters.
//  * Gather currency = random 128B line requests on the L2-MISS path:
//      r4/r7 bf16: 3.2M lines, 152MB miss traffic / 47us = 3.2 TB/s
//      r3  f32:  6.4M lines (2/user-row) sustained 3.83 TB/s  -> +20% from
//                2x outstanding misses per wave.
//      r6  sliced: request-count blowup, dead end. L2-resident req rate
//                  159 G/s proven -> request issue is NOT the cap.
//      r7  register window: NEUTRAL -> per-wave load-queue depth already
//                  sufficient; lines-per-INSTRUCTION is the lever.
//  * This round: 16 lanes/user-row, dwordx2 table loads -> 4 random lines
//    per wave-instruction (2x miss-generation rate), half the instructions.
//    If gather stays >=45us, ~3.3 TB/s is the structural ceiling -> ROOFLINE.
// ---------------------------------------------------------------------------

// Kernel 1: fp32 features -> packed bf16x2 table in d_ws.
// Thread i handles 8 floats (32B read, 16B write), fully coalesced.
__global__ __launch_bounds__(256) void convert_bf16_kernel(
    const floatx4* __restrict__ feat4,   // 1.6M float4
    uintx4*        __restrict__ table4) {// 800K uintx4
  int i = blockIdx.x * 256 + threadIdx.x;
  floatx4 f0 = __builtin_nontemporal_load(feat4 + i * 2);
  floatx4 f1 = __builtin_nontemporal_load(feat4 + i * 2 + 1);
  uintx4 r;
  r.x = pack_bf16(f0.x, f0.y);
  r.y = pack_bf16(f0.z, f0.w);
  r.z = pack_bf16(f1.x, f1.y);
  r.w = pack_bf16(f1.z, f1.w);
  table4[i] = r;  // normal store: table re-read next kernel, keep in L2
}

// Kernel 2: gather+weighted-sum, 16 lanes/user, dwordx2 row loads.
// Lane dl owns dims {4dl .. 4dl+3}; 4 users per wave -> 4 random lines
// per table-load instruction.
__global__ __launch_bounds__(256) void gather_bf16_x2_kernel(
    const uintx2* __restrict__ table2,   // [NUM_USER][16] bf16x4 (8B units)
    const int*    __restrict__ graph,    // [NUM_USER][32]
    const float*  __restrict__ matrix,   // [NUM_USER][32]
    floatx4*      __restrict__ out4) {   // [NUM_USER][16] float4
  // +1 pair pad: row stride 33*8B -> the 4 concurrent broadcast addresses
  // (user slots ul..ul+3) land in distinct bank pairs -> conflict-free.
  __shared__ int2 pairs[USERS_PER_BLOCK][K_NEIGH + 1];

  const int e    = threadIdx.x;          // 0..255
  const int base = blockIdx.x * 512;     // pair offset (16 users x 32)

  // Stage 16 users' {idx*16, w}: each thread stages 2 pairs.
#pragma unroll
  for (int h = 0; h < 2; ++h) {
    const int l  = e + h * 256;
    int   gv = __builtin_nontemporal_load(graph  + base + l);
    float wv = __builtin_nontemporal_load(matrix + base + l);
    pairs[l >> 5][l & 31] = make_int2(gv * 16, __float_as_int(wv));
  }
  __syncthreads();

  const int ul = e >> 4;                 // user slot 0..15
  const int dl = e & 15;                 // 8B lane in the 128B row
  const uintx2* tb  = table2 + dl;
  const int2*  prow = pairs[ul];

  float acc0 = 0.f, acc1 = 0.f, acc2 = 0.f, acc3 = 0.f;
#pragma unroll
  for (int kb = 0; kb < K_NEIGH / 8; ++kb) {
    uintx2 pv[8];
    float  wk[8];
#pragma unroll
    for (int j = 0; j < 8; ++j) {
      int2 pr = prow[kb * 8 + j];        // broadcast ds_read_b64 (padded)
      wk[j] = __int_as_float(pr.y);
      pv[j] = tb[pr.x];                  // global_load_dwordx2: 4 lines/wave
    }
#pragma unroll
    for (int j = 0; j < 8; ++j) {
      acc0 += wk[j] * __uint_as_float(pv[j].x << 16);          // dim 4dl
      acc1 += wk[j] * __uint_as_float(pv[j].x & 0xffff0000u);  // dim 4dl+1
      acc2 += wk[j] * __uint_as_float(pv[j].y << 16);          // dim 4dl+2
      acc3 += wk[j] * __uint_as_float(pv[j].y & 0xffff0000u);  // dim 4dl+3
    }
  }
  floatx4 r; r.x = acc0; r.y = acc1; r.z = acc2; r.w = acc3;
  // out index: u*16 + dl = blockIdx*256 + e
  __builtin_nontemporal_store(r, out4 + blockIdx.x * 256 + e);  // 16B/lane
}

// ---------------------------------------------------------------------------
// Fallback (no ws space): round-3 single-kernel f32 gather, known-good 100us.
// ---------------------------------------------------------------------------
__global__ __launch_bounds__(256) void gather_f32_lds_kernel(
    const floatx2* __restrict__ feat2,
    const int*     __restrict__ graph,
    const float*   __restrict__ matrix,
    floatx2*       __restrict__ out2) {
  __shared__ int2 pairsf[8 * K_NEIGH];
  const int e    = threadIdx.x;
  const int base = blockIdx.x * 256;
  int   gv = __builtin_nontemporal_load(graph  + base + e);
  float wv = __builtin_nontemporal_load(matrix + base + e);
  pairsf[e] = make_int2(gv, __float_as_int(wv));
  __syncthreads();
  const int u_local = e >> 5;
  const int d2      = e & 31;
  const int2* prow  = pairsf + u_local * K_NEIGH;
  float acc0 = 0.f, acc1 = 0.f;
#pragma unroll
  for (int k = 0; k < K_NEIGH; ++k) {
    int2  pr = prow[k];
    float wk = __int_as_float(pr.y);
    floatx2 p = feat2[pr.x * 32 + d2];
    acc0 += wk * p.x;
    acc1 += wk * p.y;
  }
  floatx2 r; r.x = acc0; r.y = acc1;
  __builtin_nontemporal_store(r, out2 + base + e);
}

extern "C" void kernel_launch(void* const* d_in, const int* in_sizes, int n_in,
                              void* d_out, int out_size, void* d_ws, size_t ws_size,
                              hipStream_t stream) {
  const float* features = (const float*)d_in[0];
  const int*   graph    = (const int*)d_in[1];
  const float* matrix   = (const float*)d_in[2];

  const size_t table_bytes = (size_t)NUM_USER * DIM * 2;  // 12.8 MB bf16
  if (ws_size >= table_bytes) {
    unsigned int* table = (unsigned int*)d_ws;
    // Convert: 800000 uintx4 / 256 = 3125 blocks exactly.
    convert_bf16_kernel<<<NUM_USER * DIM / 8 / 256, 256, 0, stream>>>(
        (const floatx4*)features, (uintx4*)table);
    // Gather: 100000 users / 16 per block = 6250 blocks exactly.
    gather_bf16_x2_kernel<<<NUM_USER / USERS_PER_BLOCK, 256, 0, stream>>>(
        (const uintx2*)table, graph, matrix, (floatx4*)d_out);
  } else {
    gather_f32_lds_kernel<<<NUM_USER / 8, 256, 0, stream>>>(
        (const floatx2*)features, graph, matrix, (floatx2*)d_out);
  }
}